// Round 3
// baseline (218.432 us; speedup 1.0000x reference)
//
#include <hip/hip_runtime.h>

// FusedMultiPool: out[b,s,h,w] = max_{k<8} x[b, idx[s,k], h, w]
// B=32, C=256, H=64, W=64, S=128, K=8. fp32.
//
// x[b] = 256 planes x 16KiB = 4 MiB == one XCD's L2. Pin each batch b to one
// XCD via the blockIdx%8 round-robin dispatch heuristic: XCD x processes
// b in {x, x+8, x+16, x+24}, covering ALL (s, hw-chunk) work for one b before
// moving to the next. The 4x channel-reuse across s-sets is then served from
// L2 instead of L3 -> HBM traffic drops to compulsory 128MiB read + 64MiB
// write (~32us). Non-temporal stores keep `out` from evicting x in L2.
//
// blockIdx decode (16384 blocks, 256 thr):
//   xcd   = bid & 7
//   t     = bid >> 3          in [0,2048)
//   phase = t >> 9            in [0,4)    -> b = xcd + 8*phase
//   rest  = t & 511           -> s = rest>>2, chunk = rest&3
//   hw4   = chunk*256 + tid   in [0,1024) float4s of the 16KiB plane

constexpr int Bb = 32, Cc = 256, Hh = 64, Ww = 64, Ss = 128, Kk = 8;
constexpr int HW4 = (Hh * Ww) / 4;   // 1024 float4 per channel plane

typedef float f4 __attribute__((ext_vector_type(4)));  // native vec for NT store

__global__ __launch_bounds__(256) void fmp_kernel(
    const f4* __restrict__ x4,
    const int* __restrict__ idx,
    f4*       __restrict__ out4)
{
    const unsigned bid   = blockIdx.x;
    const unsigned xcd   = bid & 7u;
    const unsigned t     = bid >> 3;
    const unsigned phase = t >> 9;          // which of this XCD's 4 batches
    const unsigned rest  = t & 511u;
    const unsigned b     = xcd + 8u * phase;        // block-uniform
    const unsigned s     = rest >> 2;               // block-uniform
    const unsigned chunk = rest & 3u;
    const unsigned hw4   = chunk * 256u + threadIdx.x;

    const int* __restrict__ ip = idx + s * Kk;      // uniform -> s_load
    const f4* __restrict__ xb = x4 + (size_t)b * (Cc * HW4) + hw4;

    f4 m = xb[(size_t)ip[0] * HW4];
    #pragma unroll
    for (int k = 1; k < Kk; ++k) {
        const f4 v = xb[(size_t)ip[k] * HW4];
        m.x = fmaxf(m.x, v.x);
        m.y = fmaxf(m.y, v.y);
        m.z = fmaxf(m.z, v.z);
        m.w = fmaxf(m.w, v.w);
    }

    const size_t o = (((size_t)b * Ss + s) * HW4) + hw4;
    __builtin_nontemporal_store(m, &out4[o]);
}

extern "C" void kernel_launch(void* const* d_in, const int* in_sizes, int n_in,
                              void* d_out, int out_size, void* d_ws, size_t ws_size,
                              hipStream_t stream) {
    const f4*  x4  = (const f4*)d_in[0];
    const int* idx = (const int*)d_in[1];
    f4*        o4  = (f4*)d_out;

    const int n4     = Bb * Ss * Hh * Ww / 4;   // 4,194,304 float4 outputs
    const int blocks = n4 / 256;                // 16384
    fmp_kernel<<<blocks, 256, 0, stream>>>(x4, idx, o4);
}

// Round 4
// 214.319 us; speedup vs baseline: 1.0192x; 1.0192x over previous
//
#include <hip/hip_runtime.h>

// FusedMultiPool: out[b,s,h,w] = max_{k<8} x[b, idx[s,k], h, w]
// B=32, C=256, H=64, W=64, S=128, K=8. fp32.
//
// LDS-staging design (cache-independent):
//   block = (b, chunk) where chunk = 32 floats (8 float4) of the 64x64 plane.
//   Phase 1: stage chunk of ALL 256 channels of x[b] into LDS (32 KiB) via
//            global_load_lds(16B). LDS slot for thread t, round r = t + 256*r
//            == c*8 + j with c = t>>3 + 32r, j = t&7  (lane-contiguous, the
//            global_load_lds requirement; no padding).
//   Phase 2: each thread computes 4 outputs (s = t>>3 + 32r, f4 lane j=t&7):
//            max over 8 LDS gathers lds[idx[s][k]*8 + j]. Bank quads
//            (c*8+j)%8 span uniformly -> structural-minimum LDS cycles.
// Global traffic is exactly compulsory: 128 MiB x read + 64 MiB NT write
// (+ idx, L2-hot). The 512 MiB gather reuse is served by LDS (~10 us agg).

constexpr int Bb = 32, Cc = 256, Hh = 64, Ww = 64, Ss = 128, Kk = 8;
constexpr int CHUNKF4 = 8;                     // 8 float4 = 32 floats/channel
constexpr int NCHUNK  = (Hh * Ww / 4) / CHUNKF4;  // 128 chunks per plane
constexpr int PLANEF4 = Hh * Ww / 4;           // 1024 float4 per plane

typedef float f4 __attribute__((ext_vector_type(4)));
typedef int   i4 __attribute__((ext_vector_type(4)));

__device__ __forceinline__ f4 fmax4(f4 a, f4 b) {
    f4 r;
    r.x = fmaxf(a.x, b.x);
    r.y = fmaxf(a.y, b.y);
    r.z = fmaxf(a.z, b.z);
    r.w = fmaxf(a.w, b.w);
    return r;
}

__global__ __launch_bounds__(256) void fmp_kernel(
    const f4* __restrict__ x4,
    const int* __restrict__ idx,
    f4*       __restrict__ out4)
{
    __shared__ f4 lds[Cc * CHUNKF4];           // 2048 f4 = 32 KiB, [c][j]

    const int t     = threadIdx.x;
    const int b     = blockIdx.x >> 7;         // block-uniform
    const int chunk = blockIdx.x & (NCHUNK - 1);
    const int j     = t & 7;
    const int c0    = t >> 3;                  // 0..31 (doubles as s-base)

    // ---- Phase 1: stage all 256 channels' chunk into LDS (direct-to-LDS) ----
    const f4* gbase = x4 + (size_t)b * (Cc * PLANEF4) + chunk * CHUNKF4 + j;
    #pragma unroll
    for (int r = 0; r < 8; ++r) {
        const f4* g = gbase + (size_t)(c0 + 32 * r) * PLANEF4;
        __builtin_amdgcn_global_load_lds(
            (const __attribute__((address_space(1))) void*)g,
            (__attribute__((address_space(3))) void*)&lds[t + 256 * r],
            16, 0, 0);
    }

    // ---- idx rows for this thread's 4 s values -> registers (L2-hot) ----
    i4 ia[4], ib[4];
    #pragma unroll
    for (int r = 0; r < 4; ++r) {
        const i4* ir = (const i4*)(idx + (c0 + 32 * r) * Kk);
        ia[r] = ir[0];
        ib[r] = ir[1];
    }

    __syncthreads();

    // ---- Phase 2: gather-max from LDS, NT store ----
    const size_t obase = (size_t)b * (Ss * PLANEF4) + chunk * CHUNKF4 + j;
    #pragma unroll
    for (int r = 0; r < 4; ++r) {
        const int s = c0 + 32 * r;
        f4 m =        lds[ia[r].x * CHUNKF4 + j];
        m = fmax4(m,  lds[ia[r].y * CHUNKF4 + j]);
        m = fmax4(m,  lds[ia[r].z * CHUNKF4 + j]);
        m = fmax4(m,  lds[ia[r].w * CHUNKF4 + j]);
        m = fmax4(m,  lds[ib[r].x * CHUNKF4 + j]);
        m = fmax4(m,  lds[ib[r].y * CHUNKF4 + j]);
        m = fmax4(m,  lds[ib[r].z * CHUNKF4 + j]);
        m = fmax4(m,  lds[ib[r].w * CHUNKF4 + j]);
        __builtin_nontemporal_store(m, &out4[obase + (size_t)s * PLANEF4]);
    }
}

extern "C" void kernel_launch(void* const* d_in, const int* in_sizes, int n_in,
                              void* d_out, int out_size, void* d_ws, size_t ws_size,
                              hipStream_t stream) {
    const f4*  x4  = (const f4*)d_in[0];
    const int* idx = (const int*)d_in[1];
    f4*        o4  = (f4*)d_out;

    const int blocks = Bb * NCHUNK;            // 32 * 128 = 4096
    fmp_kernel<<<blocks, 256, 0, stream>>>(x4, idx, o4);
}